// Round 14
// baseline (267.512 us; speedup 1.0000x reference)
//
#include <hip/hip_runtime.h>

#define N_NODES 75000
#define N_EDGES 1200000
#define DIM 64
#define SCAN_BLK 1024
#define N_SCAN_BLKS ((N_NODES + SCAN_BLK - 1) / SCAN_BLK)   // 74
#define NCOPY 8
#define HIST_BLOCKS ((N_EDGES + 1023) / 1024)               // 1172, 1024 edges/block
#define PRE_GROUPS ((HIST_BLOCKS + 7) / 8)                  // 147
#define WAVE_SLOTS (PRE_GROUPS * 8)                         // 1176
#define PRE_BLKS (PRE_GROUPS * 16)                          // 2352
#define INIT_BLKS 1172

// Broadcast lane l (wave-uniform) of v to all lanes via v_readlane (VALU).
__device__ __forceinline__ float lane_bcf(float v, int l) {
    return __int_as_float(__builtin_amdgcn_readlane(__float_as_int(v), l));
}
__device__ __forceinline__ int lane_bci(int v, int l) {
    return __builtin_amdgcn_readlane(v, l);
}

// ---------------------------------------------------------------------------
// init: zero cnt8 (600K ints, grid-strided) + block 0 computes a,b
// (f64 expressions textually identical to the old vec_precompute).
// Replaces hipMemsetAsync + vec_precompute (one dispatch instead of two).
// ---------------------------------------------------------------------------
__global__ __launch_bounds__(256) void init_kernel(
    const float* __restrict__ w_q, const float* __restrict__ w_k,
    const float* __restrict__ e1, const float* __restrict__ e2,
    double* __restrict__ a, double* __restrict__ b,
    int* __restrict__ cnt8) {
    int gtid = blockIdx.x * 256 + threadIdx.x;
    const int NT = INIT_BLKS * 256;
    for (int i = gtid; i < NCOPY * N_NODES; i += NT) cnt8[i] = 0;
    if (blockIdx.x == 0) {
        int t = threadIdx.x;
        if (t < DIM) {
            double s = 0.0;
            #pragma unroll
            for (int j = 0; j < DIM; ++j)
                s += (double)e1[j] * (double)w_k[j * DIM + t];
            a[t] = s;
        } else if (t < 2 * DIM) {
            int d = t - DIM;
            double s = 0.0;
            #pragma unroll
            for (int j = 0; j < DIM; ++j)
                s += (double)e2[j] * (double)w_q[j * DIM + d];
            b[d] = s;
        }
    }
}

// ---------------------------------------------------------------------------
// FUSED stage 1, interleaved roles (identical to R12's passing version).
// Blocks in groups of 16: slots 0-7 = hist, slots 8-15 = node_wave.
//   hist: block hb = g*8+slot handles edges [hb*1024, hb*1024+1024);
//         copy = hb&7 -> copy(e) = (e>>10)&7 recomputable in build.
//   node_wave: wave-per-node grid-strided; f64 butterfly h's (precision
//         path, bit-identical); wv via readlane broadcasts (VALU pipe).
// ---------------------------------------------------------------------------
__global__ __launch_bounds__(256, 4) void fused_pre(
    const int* __restrict__ dst, int* __restrict__ cnt8,
    int* __restrict__ rank,
    const float* __restrict__ d_u, const float* __restrict__ p_u,
    const float* __restrict__ w_v,
    const double* __restrict__ a_vec, const double* __restrict__ b_vec,
    double* __restrict__ h_src, double* __restrict__ h_dst,
    float* __restrict__ wv_out) {
    int g = blockIdx.x >> 4;
    int slot = blockIdx.x & 15;
    if (slot < 8) {
        // ---------------- hist role ----------------
        int hb = g * 8 + slot;
        if (hb >= HIST_BLOCKS) return;
        int base = hb << 10;                     // 1024 edges per hist block
        int* mycnt = cnt8 + (size_t)(hb & (NCOPY - 1)) * N_NODES;
        #pragma unroll
        for (int k = 0; k < 4; ++k) {
            int e = base + k * 256 + threadIdx.x;
            if (e < N_EDGES) rank[e] = atomicAdd(&mycnt[dst[e]], 1);
        }
    } else {
        // ---------------- node_wave role ----------------
        int wb = g * 8 + (slot - 8);
        int lane = threadIdx.x & 63;
        int wave = wb * 4 + (threadIdx.x >> 6);
        const int nwaves = WAVE_SLOTS * 4;

        float w[DIM];
        const float4* wr = (const float4*)(w_v + (size_t)lane * DIM);
        #pragma unroll
        for (int k = 0; k < DIM / 4; ++k) {
            float4 v = wr[k];
            w[4 * k + 0] = v.x; w[4 * k + 1] = v.y;
            w[4 * k + 2] = v.z; w[4 * k + 3] = v.w;
        }
        double al = a_vec[lane];
        double bl = b_vec[lane];

        for (int i = wave; i < N_NODES; i += nwaves) {
            float pl = p_u[(size_t)i * DIM + lane];
            float dl = d_u[(size_t)i * DIM + lane];

            double hs = (double)pl * al;
            #pragma unroll
            for (int off = 32; off > 0; off >>= 1) hs += __shfl_xor(hs, off, 64);
            double hd = (double)dl * bl;
            #pragma unroll
            for (int off = 32; off > 0; off >>= 1) hd += __shfl_xor(hd, off, 64);
            if (lane == 0) { h_src[i] = hs; h_dst[i] = hd; }

            float a0 = 0.f, a1 = 0.f, a2 = 0.f, a3 = 0.f;
            #pragma unroll
            for (int d = 0; d < DIM; d += 4) {
                a0 += w[d + 0] * lane_bcf(pl, d + 0);
                a1 += w[d + 1] * lane_bcf(pl, d + 1);
                a2 += w[d + 2] * lane_bcf(pl, d + 2);
                a3 += w[d + 3] * lane_bcf(pl, d + 3);
            }
            wv_out[(size_t)i * DIM + lane] = (a0 + a1) + (a2 + a3);
        }
    }
}

// CSR step 2a: fold the 8 copies (in-place exclusive prefix over copies ->
// per-copy base offsets P), degree -> cnt; per-chunk (1024-node) exclusive
// scan of degrees -> row_local; chunk total -> bsum. The cross-chunk prefix
// is applied by consumers (build/gather) from bsum — no scan23 dispatch.
__global__ __launch_bounds__(SCAN_BLK) void scan1_kernel(
    int* __restrict__ cnt8, int* __restrict__ cnt,
    int* __restrict__ row, int* __restrict__ bsum) {
    __shared__ int sh[SCAN_BLK];
    int tid = threadIdx.x;
    int i = blockIdx.x * SCAN_BLK + tid;
    int v = 0;
    if (i < N_NODES) {
        int run = 0;
        #pragma unroll
        for (int c = 0; c < NCOPY; ++c) {
            int x = cnt8[(size_t)c * N_NODES + i];
            cnt8[(size_t)c * N_NODES + i] = run;   // P[c][i] = prefix
            run += x;
        }
        v = run;
        cnt[i] = run;                              // degree
    }
    sh[tid] = v;
    __syncthreads();
    for (int off = 1; off < SCAN_BLK; off <<= 1) {
        int t = (tid >= off) ? sh[tid - off] : 0;
        __syncthreads();
        sh[tid] += t;
        __syncthreads();
    }
    if (i < N_NODES) row[i] = sh[tid] - v;   // exclusive within chunk
    if (tid == SCAN_BLK - 1) bsum[blockIdx.x] = sh[tid];
}

// CSR step 3: atomic-free scatter of src ids. Each block first builds the
// 74-entry cross-chunk exclusive prefix of bsum in LDS (serial, trivial),
// then pos = row[d] + pref[d>>10] + P[copy(e)][d] + rank[e].
__global__ __launch_bounds__(256) void build_kernel(
    const int* __restrict__ src, const int* __restrict__ dst,
    const int* __restrict__ row, const int* __restrict__ bsum,
    const int* __restrict__ cnt8,
    const int* __restrict__ rank, int* __restrict__ csr_src) {
    __shared__ int pref[N_SCAN_BLKS];
    if (threadIdx.x == 0) {
        int run = 0;
        #pragma unroll 8
        for (int k = 0; k < N_SCAN_BLKS; ++k) { pref[k] = run; run += bsum[k]; }
    }
    __syncthreads();
    int e = blockIdx.x * 256 + threadIdx.x;
    if (e >= N_EDGES) return;
    int d = dst[e];
    int copy = (e >> 10) & (NCOPY - 1);
    int pos = row[d] + pref[d >> 10] + cnt8[(size_t)copy * N_NODES + d] + rank[e];
    csr_src[pos] = src[e];
}

// ---------------------------------------------------------------------------
// Gather: one wave per dst node. Cross-chunk prefix from bsum in LDS (same
// trick as build). readlane broadcasts (VALU), x8-unrolled coalesced row
// gathers; f64 butterfly denom = precision path (bit-identical).
// ---------------------------------------------------------------------------
__global__ __launch_bounds__(256) void node_gather(
    const int* __restrict__ row, const int* __restrict__ cnt,
    const int* __restrict__ bsum,
    const int* __restrict__ csr_src,
    const double* __restrict__ h_src, const double* __restrict__ h_dst,
    const float* __restrict__ wv, float* __restrict__ out) {
    __shared__ int pref[N_SCAN_BLKS];
    if (threadIdx.x == 0) {
        int run = 0;
        #pragma unroll 8
        for (int k = 0; k < N_SCAN_BLKS; ++k) { pref[k] = run; run += bsum[k]; }
    }
    __syncthreads();

    int gtid = blockIdx.x * 256 + threadIdx.x;
    int node = gtid >> 6;
    int lane = threadIdx.x & 63;
    if (node >= N_NODES) return;

    int start = row[node] + pref[node >> 10];
    int deg = cnt[node];
    double hd = h_dst[node];

    if (deg <= 64) {
        int s0 = 0;
        double c0 = 0.0;
        if (lane < deg) {
            s0 = csr_src[start + lane];
            c0 = h_src[s0] + hd;
        }
        double r = c0;
        #pragma unroll
        for (int off = 32; off > 0; off >>= 1) r += __shfl_xor(r, off, 64);
        double inv = 1.0 / r;
        float cf0 = (lane < deg) ? (float)(c0 * inv) : 0.f;

        float acc = 0.f;
        int j = 0;
        for (; j + 8 <= deg; j += 8) {
            int   s[8];
            float c[8];
            #pragma unroll
            for (int k = 0; k < 8; ++k) {
                s[k] = lane_bci(s0, j + k);
                c[k] = lane_bcf(cf0, j + k);
            }
            float wl[8];
            #pragma unroll
            for (int k = 0; k < 8; ++k)
                wl[k] = wv[(size_t)s[k] * DIM + lane];
            #pragma unroll
            for (int k = 0; k < 8; ++k)
                acc += wl[k] * c[k];
        }
        for (; j < deg; ++j) {
            int s = lane_bci(s0, j); float cf = lane_bcf(cf0, j);
            acc += wv[(size_t)s * DIM + lane] * cf;
        }
        out[(size_t)node * DIM + lane] = acc;
    } else {
        double denom = 0.0;
        for (int base = 0; base < deg; base += 64) {
            int m = deg - base; if (m > 64) m = 64;
            double c = 0.0;
            if (lane < m) {
                int s = csr_src[start + base + lane];
                c = h_src[s] + hd;
            }
            #pragma unroll
            for (int off = 32; off > 0; off >>= 1) c += __shfl_xor(c, off, 64);
            denom += c;
        }
        double inv = 1.0 / denom;
        float acc = 0.f;
        for (int base = 0; base < deg; base += 64) {
            int m = deg - base; if (m > 64) m = 64;
            int s1 = 0; float cf1 = 0.f;
            if (lane < m) {
                s1 = csr_src[start + base + lane];
                cf1 = (float)((h_src[s1] + hd) * inv);
            }
            for (int j = 0; j < m; ++j) {
                int s = lane_bci(s1, j);
                float cf = lane_bcf(cf1, j);
                acc += wv[(size_t)s * DIM + lane] * cf;
            }
        }
        out[(size_t)node * DIM + lane] = acc;
    }
}

// ---------------------------------------------------------------------------
// Launch: 5 dispatches (was 6 kernels + 1 memset).
// ---------------------------------------------------------------------------
extern "C" void kernel_launch(void* const* d_in, const int* in_sizes, int n_in,
                              void* d_out, int out_size, void* d_ws, size_t ws_size,
                              hipStream_t stream) {
    const float* d_u = (const float*)d_in[0];
    const float* p_u = (const float*)d_in[1];
    const float* w_q = (const float*)d_in[2];
    const float* w_k = (const float*)d_in[3];
    const float* w_v = (const float*)d_in[4];
    const float* e1  = (const float*)d_in[5];
    const float* e2  = (const float*)d_in[6];
    const int*   src = (const int*)d_in[7];
    const int*   dst = (const int*)d_in[8];
    float* out = (float*)d_out;

    // Workspace: doubles first (8B aligned), then floats, then ints.
    double* a      = (double*)d_ws;
    double* b      = a + DIM;
    double* h_src  = b + DIM;
    double* h_dst  = h_src + N_NODES;
    float*  wv     = (float*)(h_dst + N_NODES);       // N_NODES*DIM floats
    int*    cnt    = (int*)(wv + (size_t)N_NODES * DIM);
    int*    row    = cnt + N_NODES;
    int*    bsum   = row + N_NODES;                   // 128 ints
    int*    cnt8   = bsum + 128;                      // NCOPY*N_NODES ints
    int*    rank   = cnt8 + (size_t)NCOPY * N_NODES;  // N_EDGES ints
    int*    csr_src= rank + N_EDGES;                  // N_EDGES ints

    init_kernel<<<INIT_BLKS, 256, 0, stream>>>(w_q, w_k, e1, e2, a, b, cnt8);

    fused_pre<<<PRE_BLKS, 256, 0, stream>>>(
        dst, cnt8, rank, d_u, p_u, w_v, a, b, h_src, h_dst, wv);

    scan1_kernel<<<N_SCAN_BLKS, SCAN_BLK, 0, stream>>>(cnt8, cnt, row, bsum);

    build_kernel<<<(N_EDGES + 255) / 256, 256, 0, stream>>>(
        src, dst, row, bsum, cnt8, rank, csr_src);

    node_gather<<<(N_NODES * 64 + 255) / 256, 256, 0, stream>>>(
        row, cnt, bsum, csr_src, h_src, h_dst, wv, out);
}

// Round 15
// 258.884 us; speedup vs baseline: 1.0333x; 1.0333x over previous
//
#include <hip/hip_runtime.h>

#define N_NODES 75000
#define N_EDGES 1200000
#define DIM 64
#define SCAN_BLK 1024
#define N_SCAN_BLKS ((N_NODES + SCAN_BLK - 1) / SCAN_BLK)   // 74
#define NCOPY 8
#define HIST_BLOCKS ((N_EDGES + 1023) / 1024)               // 1172, 1024 edges/block
#define PRE_GROUPS ((HIST_BLOCKS + 7) / 8)                  // 147
#define WAVE_SLOTS (PRE_GROUPS * 8)                         // 1176
#define PRE_BLKS (PRE_GROUPS * 16)                          // 2352
#define INIT_BLKS 1172

// Broadcast lane l (wave-uniform) of v to all lanes via v_readlane (VALU).
__device__ __forceinline__ float lane_bcf(float v, int l) {
    return __int_as_float(__builtin_amdgcn_readlane(__float_as_int(v), l));
}
__device__ __forceinline__ int lane_bci(int v, int l) {
    return __builtin_amdgcn_readlane(v, l);
}

// Physical XCD id (0..7) — HW-verified readable on gfx950 (learn_hip m09).
__device__ __forceinline__ int xcc_id() {
    unsigned v;
    asm volatile("s_getreg_b32 %0, hwreg(HW_REG_XCC_ID)" : "=s"(v));
    return (int)(v & (NCOPY - 1));
}

// ---------------------------------------------------------------------------
// init: zero cnt8 (600K ints, grid-strided) + block 0 computes a,b (f64).
// ---------------------------------------------------------------------------
__global__ __launch_bounds__(256) void init_kernel(
    const float* __restrict__ w_q, const float* __restrict__ w_k,
    const float* __restrict__ e1, const float* __restrict__ e2,
    double* __restrict__ a, double* __restrict__ b,
    int* __restrict__ cnt8) {
    int gtid = blockIdx.x * 256 + threadIdx.x;
    const int NT = INIT_BLKS * 256;
    for (int i = gtid; i < NCOPY * N_NODES; i += NT) cnt8[i] = 0;
    if (blockIdx.x == 0) {
        int t = threadIdx.x;
        if (t < DIM) {
            double s = 0.0;
            #pragma unroll
            for (int j = 0; j < DIM; ++j)
                s += (double)e1[j] * (double)w_k[j * DIM + t];
            a[t] = s;
        } else if (t < 2 * DIM) {
            int d = t - DIM;
            double s = 0.0;
            #pragma unroll
            for (int j = 0; j < DIM; ++j)
                s += (double)e2[j] * (double)w_q[j * DIM + d];
            b[d] = s;
        }
    }
}

// ---------------------------------------------------------------------------
// FUSED stage 1, interleaved roles (structure = R14's passing version).
//
// hist role CHANGE (R14 post-mortem): device-scope atomicAdd executes
// memory-side (~32B RMW -> 37MB HBM write, ~0.8 TB/s floor). Fix: copy
// index = PHYSICAL XCD id (HW_REG_XCC_ID) so each cnt8 copy is touched by
// exactly one XCD's L2, then use WORKGROUP-scope atomics -> L2-executed RMW
// (no cross-XCD coherence needed by construction; end-of-kernel release
// flushes L2 so scan1 sees the counts). copy packed into rank top bits.
// ---------------------------------------------------------------------------
__global__ __launch_bounds__(256, 4) void fused_pre(
    const int* __restrict__ dst, int* __restrict__ cnt8,
    int* __restrict__ rank,
    const float* __restrict__ d_u, const float* __restrict__ p_u,
    const float* __restrict__ w_v,
    const double* __restrict__ a_vec, const double* __restrict__ b_vec,
    double* __restrict__ h_src, double* __restrict__ h_dst,
    float* __restrict__ wv_out) {
    int g = blockIdx.x >> 4;
    int slot = blockIdx.x & 15;
    if (slot < 8) {
        // ---------------- hist role ----------------
        int hb = g * 8 + slot;
        if (hb >= HIST_BLOCKS) return;
        int base = hb << 10;                     // 1024 edges per hist block
        int copy = xcc_id();
        int* mycnt = cnt8 + (size_t)copy * N_NODES;
        int ctag = copy << 28;
        #pragma unroll
        for (int k = 0; k < 4; ++k) {
            int e = base + k * 256 + threadIdx.x;
            if (e < N_EDGES) {
                int r = __hip_atomic_fetch_add(&mycnt[dst[e]], 1,
                                               __ATOMIC_RELAXED,
                                               __HIP_MEMORY_SCOPE_WORKGROUP);
                rank[e] = ctag | r;
            }
        }
    } else {
        // ---------------- node_wave role ----------------
        int wb = g * 8 + (slot - 8);
        int lane = threadIdx.x & 63;
        int wave = wb * 4 + (threadIdx.x >> 6);
        const int nwaves = WAVE_SLOTS * 4;

        float w[DIM];
        const float4* wr = (const float4*)(w_v + (size_t)lane * DIM);
        #pragma unroll
        for (int k = 0; k < DIM / 4; ++k) {
            float4 v = wr[k];
            w[4 * k + 0] = v.x; w[4 * k + 1] = v.y;
            w[4 * k + 2] = v.z; w[4 * k + 3] = v.w;
        }
        double al = a_vec[lane];
        double bl = b_vec[lane];

        for (int i = wave; i < N_NODES; i += nwaves) {
            float pl = p_u[(size_t)i * DIM + lane];
            float dl = d_u[(size_t)i * DIM + lane];

            double hs = (double)pl * al;
            #pragma unroll
            for (int off = 32; off > 0; off >>= 1) hs += __shfl_xor(hs, off, 64);
            double hd = (double)dl * bl;
            #pragma unroll
            for (int off = 32; off > 0; off >>= 1) hd += __shfl_xor(hd, off, 64);
            if (lane == 0) { h_src[i] = hs; h_dst[i] = hd; }

            float a0 = 0.f, a1 = 0.f, a2 = 0.f, a3 = 0.f;
            #pragma unroll
            for (int d = 0; d < DIM; d += 4) {
                a0 += w[d + 0] * lane_bcf(pl, d + 0);
                a1 += w[d + 1] * lane_bcf(pl, d + 1);
                a2 += w[d + 2] * lane_bcf(pl, d + 2);
                a3 += w[d + 3] * lane_bcf(pl, d + 3);
            }
            wv_out[(size_t)i * DIM + lane] = (a0 + a1) + (a2 + a3);
        }
    }
}

// CSR step 2a: fold 8 copies (in-place exclusive prefix over copies -> P),
// degree -> cnt; per-chunk exclusive scan -> row_local; chunk total -> bsum.
__global__ __launch_bounds__(SCAN_BLK) void scan1_kernel(
    int* __restrict__ cnt8, int* __restrict__ cnt,
    int* __restrict__ row, int* __restrict__ bsum) {
    __shared__ int sh[SCAN_BLK];
    int tid = threadIdx.x;
    int i = blockIdx.x * SCAN_BLK + tid;
    int v = 0;
    if (i < N_NODES) {
        int run = 0;
        #pragma unroll
        for (int c = 0; c < NCOPY; ++c) {
            int x = cnt8[(size_t)c * N_NODES + i];
            cnt8[(size_t)c * N_NODES + i] = run;   // P[c][i] = prefix
            run += x;
        }
        v = run;
        cnt[i] = run;                              // degree
    }
    sh[tid] = v;
    __syncthreads();
    for (int off = 1; off < SCAN_BLK; off <<= 1) {
        int t = (tid >= off) ? sh[tid - off] : 0;
        __syncthreads();
        sh[tid] += t;
        __syncthreads();
    }
    if (i < N_NODES) row[i] = sh[tid] - v;   // exclusive within chunk
    if (tid == SCAN_BLK - 1) bsum[blockIdx.x] = sh[tid];
}

// CSR step 3: atomic-free scatter. Cross-chunk prefix of bsum built in LDS.
//   pos = row[d] + pref[d>>10] + P[copy(e)][d] + r, copy/r unpacked from rank.
__global__ __launch_bounds__(256) void build_kernel(
    const int* __restrict__ src, const int* __restrict__ dst,
    const int* __restrict__ row, const int* __restrict__ bsum,
    const int* __restrict__ cnt8,
    const int* __restrict__ rank, int* __restrict__ csr_src) {
    __shared__ int pref[N_SCAN_BLKS];
    if (threadIdx.x == 0) {
        int run = 0;
        #pragma unroll 8
        for (int k = 0; k < N_SCAN_BLKS; ++k) { pref[k] = run; run += bsum[k]; }
    }
    __syncthreads();
    int e = blockIdx.x * 256 + threadIdx.x;
    if (e >= N_EDGES) return;
    int d = dst[e];
    int pr = rank[e];
    int copy = pr >> 28;
    int r = pr & 0x0FFFFFFF;
    int pos = row[d] + pref[d >> 10] + cnt8[(size_t)copy * N_NODES + d] + r;
    csr_src[pos] = src[e];
}

// ---------------------------------------------------------------------------
// Gather: one wave per dst node (unchanged from R14). readlane broadcasts,
// x8-unrolled coalesced row gathers; f64 butterfly denom = precision path.
// ---------------------------------------------------------------------------
__global__ __launch_bounds__(256) void node_gather(
    const int* __restrict__ row, const int* __restrict__ cnt,
    const int* __restrict__ bsum,
    const int* __restrict__ csr_src,
    const double* __restrict__ h_src, const double* __restrict__ h_dst,
    const float* __restrict__ wv, float* __restrict__ out) {
    __shared__ int pref[N_SCAN_BLKS];
    if (threadIdx.x == 0) {
        int run = 0;
        #pragma unroll 8
        for (int k = 0; k < N_SCAN_BLKS; ++k) { pref[k] = run; run += bsum[k]; }
    }
    __syncthreads();

    int gtid = blockIdx.x * 256 + threadIdx.x;
    int node = gtid >> 6;
    int lane = threadIdx.x & 63;
    if (node >= N_NODES) return;

    int start = row[node] + pref[node >> 10];
    int deg = cnt[node];
    double hd = h_dst[node];

    if (deg <= 64) {
        int s0 = 0;
        double c0 = 0.0;
        if (lane < deg) {
            s0 = csr_src[start + lane];
            c0 = h_src[s0] + hd;
        }
        double r = c0;
        #pragma unroll
        for (int off = 32; off > 0; off >>= 1) r += __shfl_xor(r, off, 64);
        double inv = 1.0 / r;
        float cf0 = (lane < deg) ? (float)(c0 * inv) : 0.f;

        float acc = 0.f;
        int j = 0;
        for (; j + 8 <= deg; j += 8) {
            int   s[8];
            float c[8];
            #pragma unroll
            for (int k = 0; k < 8; ++k) {
                s[k] = lane_bci(s0, j + k);
                c[k] = lane_bcf(cf0, j + k);
            }
            float wl[8];
            #pragma unroll
            for (int k = 0; k < 8; ++k)
                wl[k] = wv[(size_t)s[k] * DIM + lane];
            #pragma unroll
            for (int k = 0; k < 8; ++k)
                acc += wl[k] * c[k];
        }
        for (; j < deg; ++j) {
            int s = lane_bci(s0, j); float cf = lane_bcf(cf0, j);
            acc += wv[(size_t)s * DIM + lane] * cf;
        }
        out[(size_t)node * DIM + lane] = acc;
    } else {
        double denom = 0.0;
        for (int base = 0; base < deg; base += 64) {
            int m = deg - base; if (m > 64) m = 64;
            double c = 0.0;
            if (lane < m) {
                int s = csr_src[start + base + lane];
                c = h_src[s] + hd;
            }
            #pragma unroll
            for (int off = 32; off > 0; off >>= 1) c += __shfl_xor(c, off, 64);
            denom += c;
        }
        double inv = 1.0 / denom;
        float acc = 0.f;
        for (int base = 0; base < deg; base += 64) {
            int m = deg - base; if (m > 64) m = 64;
            int s1 = 0; float cf1 = 0.f;
            if (lane < m) {
                s1 = csr_src[start + base + lane];
                cf1 = (float)((h_src[s1] + hd) * inv);
            }
            for (int j = 0; j < m; ++j) {
                int s = lane_bci(s1, j);
                float cf = lane_bcf(cf1, j);
                acc += wv[(size_t)s * DIM + lane] * cf;
            }
        }
        out[(size_t)node * DIM + lane] = acc;
    }
}

// ---------------------------------------------------------------------------
// Launch: 5 dispatches.
// ---------------------------------------------------------------------------
extern "C" void kernel_launch(void* const* d_in, const int* in_sizes, int n_in,
                              void* d_out, int out_size, void* d_ws, size_t ws_size,
                              hipStream_t stream) {
    const float* d_u = (const float*)d_in[0];
    const float* p_u = (const float*)d_in[1];
    const float* w_q = (const float*)d_in[2];
    const float* w_k = (const float*)d_in[3];
    const float* w_v = (const float*)d_in[4];
    const float* e1  = (const float*)d_in[5];
    const float* e2  = (const float*)d_in[6];
    const int*   src = (const int*)d_in[7];
    const int*   dst = (const int*)d_in[8];
    float* out = (float*)d_out;

    // Workspace: doubles first (8B aligned), then floats, then ints.
    double* a      = (double*)d_ws;
    double* b      = a + DIM;
    double* h_src  = b + DIM;
    double* h_dst  = h_src + N_NODES;
    float*  wv     = (float*)(h_dst + N_NODES);       // N_NODES*DIM floats
    int*    cnt    = (int*)(wv + (size_t)N_NODES * DIM);
    int*    row    = cnt + N_NODES;
    int*    bsum   = row + N_NODES;                   // 128 ints
    int*    cnt8   = bsum + 128;                      // NCOPY*N_NODES ints
    int*    rank   = cnt8 + (size_t)NCOPY * N_NODES;  // N_EDGES ints
    int*    csr_src= rank + N_EDGES;                  // N_EDGES ints

    init_kernel<<<INIT_BLKS, 256, 0, stream>>>(w_q, w_k, e1, e2, a, b, cnt8);

    fused_pre<<<PRE_BLKS, 256, 0, stream>>>(
        dst, cnt8, rank, d_u, p_u, w_v, a, b, h_src, h_dst, wv);

    scan1_kernel<<<N_SCAN_BLKS, SCAN_BLK, 0, stream>>>(cnt8, cnt, row, bsum);

    build_kernel<<<(N_EDGES + 255) / 256, 256, 0, stream>>>(
        src, dst, row, bsum, cnt8, rank, csr_src);

    node_gather<<<(N_NODES * 64 + 255) / 256, 256, 0, stream>>>(
        row, cnt, bsum, csr_src, h_src, h_dst, wv, out);
}